// Round 3
// baseline (613.512 us; speedup 1.0000x reference)
//
#include <hip/hip_runtime.h>
#include <hip/hip_bf16.h>
#include <math.h>

#define N_NODES 50000

// ---------------- degree (int histogram) ----------------

__global__ void deg_kernel(const int* __restrict__ dst, int* __restrict__ deg, int E) {
    int e = blockIdx.x * blockDim.x + threadIdx.x;
    if (e < E) atomicAdd(&deg[dst[e]], 1);
}

__global__ void inv_sqrt_kernel(const int* __restrict__ deg, float* __restrict__ inv, int n) {
    int i = blockIdx.x * blockDim.x + threadIdx.x;
    if (i < n) inv[i] = rsqrtf(fmaxf((float)deg[i], 1.0f));
}

// ---------------- exclusive prefix scan (single block, 1024 threads) ----------------
// also writes the cursor copy for the fill pass

__global__ void scan_kernel(const int* __restrict__ deg, int* __restrict__ rowptr,
                            int* __restrict__ cursor, int n) {
    __shared__ int part[1024];
    int tid = threadIdx.x;
    int per = (n + 1023) >> 10;
    int base = tid * per;
    int sum = 0;
    for (int i = 0; i < per; ++i) {
        int idx = base + i;
        if (idx < n) sum += deg[idx];
    }
    part[tid] = sum;
    __syncthreads();
    // Hillis-Steele inclusive scan
    for (int off = 1; off < 1024; off <<= 1) {
        int v = (tid >= off) ? part[tid - off] : 0;
        __syncthreads();
        part[tid] += v;
        __syncthreads();
    }
    int run = part[tid] - sum;  // exclusive prefix of this chunk
    for (int i = 0; i < per; ++i) {
        int idx = base + i;
        if (idx < n) { rowptr[idx] = run; cursor[idx] = run; run += deg[idx]; }
    }
    if (tid == 1023) rowptr[n] = part[1023];
}

// ---------------- bucket edges by dst (counting sort fill) ----------------

__global__ void fill_kernel(const int* __restrict__ src, const int* __restrict__ dst,
                            const float* __restrict__ inv, int* __restrict__ cursor,
                            int* __restrict__ src_s, float* __restrict__ norm_s, int E) {
    int e = blockIdx.x * blockDim.x + threadIdx.x;
    if (e >= E) return;
    int s = src[e];
    int d = dst[e];
    int pos = atomicAdd(&cursor[d], 1);
    src_s[pos] = s;
    norm_s[pos] = inv[s] * inv[d];
}

// ---------------- gather aggregation: one wave per node ----------------

template<int F>
__global__ void gather_agg_kernel(const float* __restrict__ x, const int* __restrict__ rowptr,
                                  const int* __restrict__ src_s, const float* __restrict__ norm_s,
                                  float* __restrict__ agg) {
    int node = blockIdx.x * 4 + (threadIdx.x >> 6);
    if (node >= N_NODES) return;
    int lane = threadIdx.x & 63;
    int beg = rowptr[node];
    int end = rowptr[node + 1];

    if constexpr (F == 128) {
        float2 acc = {0.0f, 0.0f};
        for (int p = beg; p < end; ++p) {
            int s = src_s[p];
            float nv = norm_s[p];
            float2 v = ((const float2*)(x + (size_t)s * F))[lane];
            acc.x = fmaf(v.x, nv, acc.x);
            acc.y = fmaf(v.y, nv, acc.y);
        }
        ((float2*)(agg + (size_t)node * F))[lane] = acc;
    } else {
        float4 acc = {0.0f, 0.0f, 0.0f, 0.0f};
        for (int p = beg; p < end; ++p) {
            int s = src_s[p];
            float nv = norm_s[p];
            float4 v = ((const float4*)(x + (size_t)s * F))[lane];
            acc.x = fmaf(v.x, nv, acc.x);
            acc.y = fmaf(v.y, nv, acc.y);
            acc.z = fmaf(v.z, nv, acc.z);
            acc.w = fmaf(v.w, nv, acc.w);
        }
        ((float4*)(agg + (size_t)node * F))[lane] = acc;
    }
}

// ---------------- register-tiled GEMM + bias + ReLU ----------------
// C[M,256] = relu(A[M,K] @ W[K,256] + b). Block tile 128x128, thread tile 8x8,
// BK=16, A staged transposed in LDS. W row stride hardcoded 256.

template<int K>
__global__ __launch_bounds__(256) void gemm_rt_kernel(const float* __restrict__ A,
                                                      const float* __restrict__ W,
                                                      const float* __restrict__ b,
                                                      float* __restrict__ out, int M) {
    constexpr int BM = 128, BN = 128, BK = 16;
    __shared__ float As[BK][BM];   // transposed: As[k][m]
    __shared__ float Bs[BK][BN];

    int tid = threadIdx.x;
    int tx = tid & 15;        // 0..15 -> output col group
    int ty = tid >> 4;        // 0..15 -> output row group
    int row0 = blockIdx.x * BM;
    int col0 = blockIdx.y * BN;

    float acc[8][8];
    #pragma unroll
    for (int i = 0; i < 8; ++i)
        #pragma unroll
        for (int j = 0; j < 8; ++j) acc[i][j] = 0.0f;

    for (int kk = 0; kk < K; kk += BK) {
        // stage A tile (BM x BK), transposed into As[k][m]
        #pragma unroll
        for (int f = tid; f < BM * BK / 4; f += 256) {
            int r = f >> 2;            // 0..127
            int c4 = (f & 3) << 2;     // 0,4,8,12
            int row = row0 + r;
            float4 v = make_float4(0.f, 0.f, 0.f, 0.f);
            if (row < M) v = *(const float4*)(A + (size_t)row * K + kk + c4);
            As[c4 + 0][r] = v.x;
            As[c4 + 1][r] = v.y;
            As[c4 + 2][r] = v.z;
            As[c4 + 3][r] = v.w;
        }
        // stage B tile (BK x BN), natural layout
        #pragma unroll
        for (int f = tid; f < BK * BN / 4; f += 256) {
            int r = f >> 5;            // 0..15
            int c4 = (f & 31) << 2;    // 0..124
            *(float4*)&Bs[r][c4] = *(const float4*)(W + (size_t)(kk + r) * 256 + col0 + c4);
        }
        __syncthreads();

        #pragma unroll
        for (int k = 0; k < BK; ++k) {
            float a[8], bb[8];
            *(float4*)&a[0]  = *(float4*)&As[k][ty * 4];
            *(float4*)&a[4]  = *(float4*)&As[k][64 + ty * 4];
            *(float4*)&bb[0] = *(float4*)&Bs[k][tx * 4];
            *(float4*)&bb[4] = *(float4*)&Bs[k][64 + tx * 4];
            #pragma unroll
            for (int i = 0; i < 8; ++i)
                #pragma unroll
                for (int j = 0; j < 8; ++j)
                    acc[i][j] = fmaf(a[i], bb[j], acc[i][j]);
        }
        __syncthreads();
    }

    // epilogue: bias + relu, guarded stores
    float4 blo = *(const float4*)(b + col0 + tx * 4);
    float4 bhi = *(const float4*)(b + col0 + 64 + tx * 4);
    #pragma unroll
    for (int i = 0; i < 8; ++i) {
        int row = row0 + (i < 4 ? ty * 4 + i : 64 + ty * 4 + (i - 4));
        if (row >= M) continue;
        float* orow = out + (size_t)row * 256 + col0;
        float4 lo, hi;
        lo.x = fmaxf(acc[i][0] + blo.x, 0.f);
        lo.y = fmaxf(acc[i][1] + blo.y, 0.f);
        lo.z = fmaxf(acc[i][2] + blo.z, 0.f);
        lo.w = fmaxf(acc[i][3] + blo.w, 0.f);
        hi.x = fmaxf(acc[i][4] + bhi.x, 0.f);
        hi.y = fmaxf(acc[i][5] + bhi.y, 0.f);
        hi.z = fmaxf(acc[i][6] + bhi.z, 0.f);
        hi.w = fmaxf(acc[i][7] + bhi.w, 0.f);
        *(float4*)(orow + tx * 4) = lo;
        *(float4*)(orow + 64 + tx * 4) = hi;
    }
}

// ---------------- dense head + softmax ----------------
// one wave (64 threads) per row; C=40 classes, K=256.

__global__ void dense_softmax_kernel(const float* __restrict__ h, const float* __restrict__ Wd,
                                     const float* __restrict__ bd, float* __restrict__ out) {
    int row = blockIdx.x;
    int lane = threadIdx.x; // 0..63
    __shared__ float hs[256];
    ((float4*)hs)[lane] = ((const float4*)(h + (size_t)row * 256))[lane];
    __syncthreads();

    float logit = -INFINITY;
    if (lane < 40) {
        float acc = bd[lane];
        #pragma unroll 8
        for (int k = 0; k < 256; ++k) acc = fmaf(hs[k], Wd[(size_t)k * 40 + lane], acc);
        logit = acc;
    }
    float m = logit;
    #pragma unroll
    for (int off = 32; off > 0; off >>= 1) m = fmaxf(m, __shfl_xor(m, off));
    float e = (lane < 40) ? expf(logit - m) : 0.0f;
    float s = e;
    #pragma unroll
    for (int off = 32; off > 0; off >>= 1) s += __shfl_xor(s, off);
    if (lane < 40) out[(size_t)row * 40 + lane] = e / s;
}

// ---------------- launch ----------------

extern "C" void kernel_launch(void* const* d_in, const int* in_sizes, int n_in,
                              void* d_out, int out_size, void* d_ws, size_t ws_size,
                              hipStream_t stream) {
    const float* x  = (const float*)d_in[0];
    const int*   ei = (const int*)d_in[1];
    const float* W1 = (const float*)d_in[2];
    const float* b1 = (const float*)d_in[3];
    const float* W2 = (const float*)d_in[4];
    const float* b2 = (const float*)d_in[5];
    const float* Wd = (const float*)d_in[6];
    const float* bd = (const float*)d_in[7];
    float* out = (float*)d_out;

    const int N = N_NODES;
    const int E = in_sizes[1] / 2;
    const int* src = ei;
    const int* dst = ei + E;

    // workspace layout (bytes, 1KB-aligned). Total ~108 MB.
    char* ws = (char*)d_ws;
    size_t off = 0;
    auto alloc = [&](size_t bytes) { char* p = ws + off; off += (bytes + 1023) & ~(size_t)1023; return p; };
    int*   deg    = (int*)alloc((size_t)N * 4);
    float* inv    = (float*)alloc((size_t)N * 4);
    int*   rowptr = (int*)alloc((size_t)(N + 1) * 4);
    int*   cursor = (int*)alloc((size_t)N * 4);
    int*   src_s  = (int*)alloc((size_t)E * 4);
    float* norm_s = (float*)alloc((size_t)E * 4);
    float* h1     = (float*)alloc((size_t)N * 256 * 4);
    float* agg2   = (float*)alloc((size_t)N * 256 * 4);
    float* agg1   = agg2;   // agg1 [N,128] aliases agg2 region (lifetimes disjoint)
    float* h2     = h1;     // h2 reuses h1

    hipMemsetAsync(deg, 0, (size_t)N * 4, stream);

    // degree -> inv_sqrt -> rowptr(+cursor) -> bucketed (src_s, norm_s)
    deg_kernel<<<(E + 255) / 256, 256, 0, stream>>>(dst, deg, E);
    inv_sqrt_kernel<<<(N + 255) / 256, 256, 0, stream>>>(deg, inv, N);
    scan_kernel<<<1, 1024, 0, stream>>>(deg, rowptr, cursor, N);
    fill_kernel<<<(E + 255) / 256, 256, 0, stream>>>(src, dst, inv, cursor, src_s, norm_s, E);

    // conv1: gather-aggregate into agg1 [N,128], then h1 = relu(agg1@W1 + b1)
    gather_agg_kernel<128><<<(N + 3) / 4, 256, 0, stream>>>(x, rowptr, src_s, norm_s, agg1);
    {
        dim3 grid((N + 127) / 128, 2);
        gemm_rt_kernel<128><<<grid, 256, 0, stream>>>(agg1, W1, b1, h1, N);
    }

    // conv2: gather-aggregate h1 into agg2 [N,256], then h2 = relu(agg2@W2 + b2)
    gather_agg_kernel<256><<<(N + 3) / 4, 256, 0, stream>>>(h1, rowptr, src_s, norm_s, agg2);
    {
        dim3 grid((N + 127) / 128, 2);
        gemm_rt_kernel<256><<<grid, 256, 0, stream>>>(agg2, W2, b2, h2, N);
    }

    // dense + softmax
    dense_softmax_kernel<<<N, 64, 0, stream>>>(h2, Wd, bd, out);
}

// Round 4
// 561.585 us; speedup vs baseline: 1.0925x; 1.0925x over previous
//
#include <hip/hip_runtime.h>
#include <hip/hip_bf16.h>
#include <math.h>

#define N_NODES 50000

// ---------------- degree (int histogram) ----------------

__global__ void deg_kernel(const int* __restrict__ dst, int* __restrict__ deg, int E) {
    int e = blockIdx.x * blockDim.x + threadIdx.x;
    if (e < E) atomicAdd(&deg[dst[e]], 1);
}

__global__ void inv_sqrt_kernel(const int* __restrict__ deg, float* __restrict__ inv, int n) {
    int i = blockIdx.x * blockDim.x + threadIdx.x;
    if (i < n) inv[i] = rsqrtf(fmaxf((float)deg[i], 1.0f));
}

// ---------------- multi-block exclusive scan ----------------
// p1: per-block (1024 elems) totals; p2: scan 49 totals (1 tiny block);
// p3: per-block rescan + offset, write rowptr & cursor.

__global__ void scan_p1(const int* __restrict__ deg, int* __restrict__ bsum, int n) {
    int t = threadIdx.x;                    // 256 threads
    int base = blockIdx.x * 1024 + t * 4;
    int4 v = make_int4(0, 0, 0, 0);
    if (base + 3 < n) v = *(const int4*)(deg + base);
    else {
        if (base + 0 < n) v.x = deg[base + 0];
        if (base + 1 < n) v.y = deg[base + 1];
        if (base + 2 < n) v.z = deg[base + 2];
    }
    int s = v.x + v.y + v.z + v.w;
    #pragma unroll
    for (int off = 32; off > 0; off >>= 1) s += __shfl_xor(s, off);
    __shared__ int wpart[4];
    if ((t & 63) == 0) wpart[t >> 6] = s;
    __syncthreads();
    if (t == 0) bsum[blockIdx.x] = wpart[0] + wpart[1] + wpart[2] + wpart[3];
}

__global__ void scan_p2(int* __restrict__ bsum, int nb, int* __restrict__ rowptr, int n) {
    int t = threadIdx.x;                    // 64 threads, nb <= 64
    int v = (t < nb) ? bsum[t] : 0;
    int sc = v;
    #pragma unroll
    for (int off = 1; off < 64; off <<= 1) {
        int u = __shfl_up(sc, off);
        if (t >= off) sc += u;
    }
    if (t < nb) bsum[t] = sc - v;           // exclusive block offsets
    if (t == 63) rowptr[n] = sc;            // grand total
}

__global__ void scan_p3(const int* __restrict__ deg, const int* __restrict__ bsum,
                        int* __restrict__ rowptr, int* __restrict__ cursor, int n) {
    int t = threadIdx.x;                    // 256 threads
    int base = blockIdx.x * 1024 + t * 4;
    int4 v = make_int4(0, 0, 0, 0);
    if (base + 3 < n) v = *(const int4*)(deg + base);
    else {
        if (base + 0 < n) v.x = deg[base + 0];
        if (base + 1 < n) v.y = deg[base + 1];
        if (base + 2 < n) v.z = deg[base + 2];
    }
    int s = v.x + v.y + v.z + v.w;
    int lane = t & 63;
    int sc = s;
    #pragma unroll
    for (int off = 1; off < 64; off <<= 1) {
        int u = __shfl_up(sc, off);
        if (lane >= off) sc += u;
    }
    __shared__ int wpart[4], woff[4];
    if (lane == 63) wpart[t >> 6] = sc;
    __syncthreads();
    if (t == 0) { int a = 0; for (int i = 0; i < 4; ++i) { woff[i] = a; a += wpart[i]; } }
    __syncthreads();
    int run = bsum[blockIdx.x] + woff[t >> 6] + (sc - s);
    if (base + 0 < n) { rowptr[base + 0] = run; cursor[base + 0] = run; run += v.x; }
    if (base + 1 < n) { rowptr[base + 1] = run; cursor[base + 1] = run; run += v.y; }
    if (base + 2 < n) { rowptr[base + 2] = run; cursor[base + 2] = run; run += v.z; }
    if (base + 3 < n) { rowptr[base + 3] = run; cursor[base + 3] = run; run += v.w; }
}

// ---------------- bucket edges by dst (counting sort fill) ----------------

__global__ void fill_kernel(const int* __restrict__ src, const int* __restrict__ dst,
                            const float* __restrict__ inv, int* __restrict__ cursor,
                            int* __restrict__ src_s, float* __restrict__ norm_s, int E) {
    int e = blockIdx.x * blockDim.x + threadIdx.x;
    if (e >= E) return;
    int s = src[e];
    int d = dst[e];
    int pos = atomicAdd(&cursor[d], 1);
    src_s[pos] = s;
    norm_s[pos] = inv[s] * inv[d];
}

// ---------------- gather aggregation: one wave per node ----------------

template<int F>
__global__ void gather_agg_kernel(const float* __restrict__ x, const int* __restrict__ rowptr,
                                  const int* __restrict__ src_s, const float* __restrict__ norm_s,
                                  float* __restrict__ agg) {
    int node = blockIdx.x * 4 + (threadIdx.x >> 6);
    if (node >= N_NODES) return;
    int lane = threadIdx.x & 63;
    int beg = rowptr[node];
    int end = rowptr[node + 1];

    if constexpr (F == 128) {
        float2 acc = {0.0f, 0.0f};
        for (int p = beg; p < end; ++p) {
            int s = src_s[p];
            float nv = norm_s[p];
            float2 v = ((const float2*)(x + (size_t)s * F))[lane];
            acc.x = fmaf(v.x, nv, acc.x);
            acc.y = fmaf(v.y, nv, acc.y);
        }
        ((float2*)(agg + (size_t)node * F))[lane] = acc;
    } else {
        float4 acc = {0.0f, 0.0f, 0.0f, 0.0f};
        for (int p = beg; p < end; ++p) {
            int s = src_s[p];
            float nv = norm_s[p];
            float4 v = ((const float4*)(x + (size_t)s * F))[lane];
            acc.x = fmaf(v.x, nv, acc.x);
            acc.y = fmaf(v.y, nv, acc.y);
            acc.z = fmaf(v.z, nv, acc.z);
            acc.w = fmaf(v.w, nv, acc.w);
        }
        ((float4*)(agg + (size_t)node * F))[lane] = acc;
    }
}

// ---------------- double-buffered register-tiled GEMM + bias + ReLU ----------------
// C[M,256] = relu(A[M,K] @ W[K,256] + b). Block tile 128x128, thread tile 8x8,
// BK=16, LDS double-buffered with register prefetch (1 barrier/iter).
// As padded to stride 132 -> staging transpose writes are 2-way (free).

template<int K>
__global__ __launch_bounds__(256) void gemm_rt_kernel(const float* __restrict__ A,
                                                      const float* __restrict__ W,
                                                      const float* __restrict__ b,
                                                      float* __restrict__ out, int M) {
    constexpr int BM = 128, BN = 128, BK = 16;
    constexpr int LDA = BM + 4;
    __shared__ float As[2][BK][LDA];
    __shared__ float Bs[2][BK][BN];

    int tid = threadIdx.x;
    int tx = tid & 15;
    int ty = tid >> 4;
    int row0 = blockIdx.x * BM;
    int col0 = blockIdx.y * BN;

    // staging slots: A 512 float4s / 256 thr = 2 each; B 512 float4s = 2 each
    int ar0 = tid >> 2;                 // 0..63
    int ac0 = (tid & 3) << 2;           // 0,4,8,12
    int ar1 = ar0 + 64;                 // 64..127
    int br0 = tid >> 5;                 // 0..7
    int bc0 = (tid & 31) << 2;          // 0..124
    int br1 = br0 + 8;

    float4 ra0, ra1, rb0, rb1;

    float acc[8][8];
    #pragma unroll
    for (int i = 0; i < 8; ++i)
        #pragma unroll
        for (int j = 0; j < 8; ++j) acc[i][j] = 0.0f;

    // prologue: load tile 0
    {
        int rA0 = row0 + ar0, rA1 = row0 + ar1;
        ra0 = (rA0 < M) ? *(const float4*)(A + (size_t)rA0 * K + ac0) : make_float4(0, 0, 0, 0);
        ra1 = (rA1 < M) ? *(const float4*)(A + (size_t)rA1 * K + ac0) : make_float4(0, 0, 0, 0);
        rb0 = *(const float4*)(W + (size_t)br0 * 256 + col0 + bc0);
        rb1 = *(const float4*)(W + (size_t)br1 * 256 + col0 + bc0);
        As[0][ac0 + 0][ar0] = ra0.x;
        As[0][ac0 + 1][ar0] = ra0.y;
        As[0][ac0 + 2][ar0] = ra0.z;
        As[0][ac0 + 3][ar0] = ra0.w;
        As[0][ac0 + 0][ar1] = ra1.x;
        As[0][ac0 + 1][ar1] = ra1.y;
        As[0][ac0 + 2][ar1] = ra1.z;
        As[0][ac0 + 3][ar1] = ra1.w;
        *(float4*)&Bs[0][br0][bc0] = rb0;
        *(float4*)&Bs[0][br1][bc0] = rb1;
    }
    __syncthreads();

    constexpr int NT = K / BK;
    #pragma unroll 1
    for (int t = 0; t < NT; ++t) {
        int cur = t & 1;
        if (t + 1 < NT) {   // issue next tile's global loads (latency hides under compute)
            int kk = (t + 1) * BK;
            int rA0 = row0 + ar0, rA1 = row0 + ar1;
            ra0 = (rA0 < M) ? *(const float4*)(A + (size_t)rA0 * K + kk + ac0) : make_float4(0, 0, 0, 0);
            ra1 = (rA1 < M) ? *(const float4*)(A + (size_t)rA1 * K + kk + ac0) : make_float4(0, 0, 0, 0);
            rb0 = *(const float4*)(W + (size_t)(kk + br0) * 256 + col0 + bc0);
            rb1 = *(const float4*)(W + (size_t)(kk + br1) * 256 + col0 + bc0);
        }
        #pragma unroll
        for (int k = 0; k < BK; ++k) {
            float a[8], bb[8];
            *(float4*)&a[0]  = *(float4*)&As[cur][k][ty * 4];
            *(float4*)&a[4]  = *(float4*)&As[cur][k][64 + ty * 4];
            *(float4*)&bb[0] = *(float4*)&Bs[cur][k][tx * 4];
            *(float4*)&bb[4] = *(float4*)&Bs[cur][k][64 + tx * 4];
            #pragma unroll
            for (int i = 0; i < 8; ++i)
                #pragma unroll
                for (int j = 0; j < 8; ++j)
                    acc[i][j] = fmaf(a[i], bb[j], acc[i][j]);
        }
        if (t + 1 < NT) {
            int nb = cur ^ 1;
            As[nb][ac0 + 0][ar0] = ra0.x;
            As[nb][ac0 + 1][ar0] = ra0.y;
            As[nb][ac0 + 2][ar0] = ra0.z;
            As[nb][ac0 + 3][ar0] = ra0.w;
            As[nb][ac0 + 0][ar1] = ra1.x;
            As[nb][ac0 + 1][ar1] = ra1.y;
            As[nb][ac0 + 2][ar1] = ra1.z;
            As[nb][ac0 + 3][ar1] = ra1.w;
            *(float4*)&Bs[nb][br0][bc0] = rb0;
            *(float4*)&Bs[nb][br1][bc0] = rb1;
        }
        __syncthreads();
    }

    // epilogue: bias + relu, guarded stores
    float4 blo = *(const float4*)(b + col0 + tx * 4);
    float4 bhi = *(const float4*)(b + col0 + 64 + tx * 4);
    #pragma unroll
    for (int i = 0; i < 8; ++i) {
        int row = row0 + (i < 4 ? ty * 4 + i : 64 + ty * 4 + (i - 4));
        if (row >= M) continue;
        float* orow = out + (size_t)row * 256 + col0;
        float4 lo, hi;
        lo.x = fmaxf(acc[i][0] + blo.x, 0.f);
        lo.y = fmaxf(acc[i][1] + blo.y, 0.f);
        lo.z = fmaxf(acc[i][2] + blo.z, 0.f);
        lo.w = fmaxf(acc[i][3] + blo.w, 0.f);
        hi.x = fmaxf(acc[i][4] + bhi.x, 0.f);
        hi.y = fmaxf(acc[i][5] + bhi.y, 0.f);
        hi.z = fmaxf(acc[i][6] + bhi.z, 0.f);
        hi.w = fmaxf(acc[i][7] + bhi.w, 0.f);
        *(float4*)(orow + tx * 4) = lo;
        *(float4*)(orow + 64 + tx * 4) = hi;
    }
}

// ---------------- dense head + softmax ----------------
// one wave (64 threads) per row; C=40 classes, K=256.

__global__ void dense_softmax_kernel(const float* __restrict__ h, const float* __restrict__ Wd,
                                     const float* __restrict__ bd, float* __restrict__ out) {
    int row = blockIdx.x;
    int lane = threadIdx.x; // 0..63
    __shared__ float hs[256];
    ((float4*)hs)[lane] = ((const float4*)(h + (size_t)row * 256))[lane];
    __syncthreads();

    float logit = -INFINITY;
    if (lane < 40) {
        float acc = bd[lane];
        #pragma unroll 8
        for (int k = 0; k < 256; ++k) acc = fmaf(hs[k], Wd[(size_t)k * 40 + lane], acc);
        logit = acc;
    }
    float m = logit;
    #pragma unroll
    for (int off = 32; off > 0; off >>= 1) m = fmaxf(m, __shfl_xor(m, off));
    float e = (lane < 40) ? expf(logit - m) : 0.0f;
    float s = e;
    #pragma unroll
    for (int off = 32; off > 0; off >>= 1) s += __shfl_xor(s, off);
    if (lane < 40) out[(size_t)row * 40 + lane] = e / s;
}

// ---------------- launch ----------------

extern "C" void kernel_launch(void* const* d_in, const int* in_sizes, int n_in,
                              void* d_out, int out_size, void* d_ws, size_t ws_size,
                              hipStream_t stream) {
    const float* x  = (const float*)d_in[0];
    const int*   ei = (const int*)d_in[1];
    const float* W1 = (const float*)d_in[2];
    const float* b1 = (const float*)d_in[3];
    const float* W2 = (const float*)d_in[4];
    const float* b2 = (const float*)d_in[5];
    const float* Wd = (const float*)d_in[6];
    const float* bd = (const float*)d_in[7];
    float* out = (float*)d_out;

    const int N = N_NODES;
    const int E = in_sizes[1] / 2;
    const int* src = ei;
    const int* dst = ei + E;

    // workspace layout (bytes, 1KB-aligned). Total ~108 MB.
    char* ws = (char*)d_ws;
    size_t off = 0;
    auto alloc = [&](size_t bytes) { char* p = ws + off; off += (bytes + 1023) & ~(size_t)1023; return p; };
    int*   deg    = (int*)alloc((size_t)N * 4);
    float* inv    = (float*)alloc((size_t)N * 4);
    int*   rowptr = (int*)alloc((size_t)(N + 1) * 4);
    int*   cursor = (int*)alloc((size_t)N * 4);
    int*   bsum   = (int*)alloc((size_t)64 * 4);
    int*   src_s  = (int*)alloc((size_t)E * 4);
    float* norm_s = (float*)alloc((size_t)E * 4);
    float* h1     = (float*)alloc((size_t)N * 256 * 4);
    float* agg2   = (float*)alloc((size_t)N * 256 * 4);
    float* agg1   = agg2;   // agg1 [N,128] aliases agg2 region (lifetimes disjoint)
    float* h2     = h1;     // h2 reuses h1

    hipMemsetAsync(deg, 0, (size_t)N * 4, stream);

    const int nb = (N + 1023) / 1024;   // 49 scan blocks

    // degree -> inv_sqrt -> rowptr(+cursor) -> bucketed (src_s, norm_s)
    deg_kernel<<<(E + 255) / 256, 256, 0, stream>>>(dst, deg, E);
    inv_sqrt_kernel<<<(N + 255) / 256, 256, 0, stream>>>(deg, inv, N);
    scan_p1<<<nb, 256, 0, stream>>>(deg, bsum, N);
    scan_p2<<<1, 64, 0, stream>>>(bsum, nb, rowptr, N);
    scan_p3<<<nb, 256, 0, stream>>>(deg, bsum, rowptr, cursor, N);
    fill_kernel<<<(E + 255) / 256, 256, 0, stream>>>(src, dst, inv, cursor, src_s, norm_s, E);

    // conv1: gather-aggregate into agg1 [N,128], then h1 = relu(agg1@W1 + b1)
    gather_agg_kernel<128><<<(N + 3) / 4, 256, 0, stream>>>(x, rowptr, src_s, norm_s, agg1);
    {
        dim3 grid((N + 127) / 128, 2);
        gemm_rt_kernel<128><<<grid, 256, 0, stream>>>(agg1, W1, b1, h1, N);
    }

    // conv2: gather-aggregate h1 into agg2 [N,256], then h2 = relu(agg2@W2 + b2)
    gather_agg_kernel<256><<<(N + 3) / 4, 256, 0, stream>>>(h1, rowptr, src_s, norm_s, agg2);
    {
        dim3 grid((N + 127) / 128, 2);
        gemm_rt_kernel<256><<<grid, 256, 0, stream>>>(agg2, W2, b2, h2, N);
    }

    // dense + softmax
    dense_softmax_kernel<<<N, 64, 0, stream>>>(h2, Wd, bd, out);
}

// Round 5
// 411.004 us; speedup vs baseline: 1.4927x; 1.3664x over previous
//
#include <hip/hip_runtime.h>
#include <hip/hip_bf16.h>
#include <math.h>

#define N_NODES 50000

// ---------------- degree (int histogram) ----------------

__global__ void deg_kernel(const int* __restrict__ dst, int* __restrict__ deg, int E) {
    int e = blockIdx.x * blockDim.x + threadIdx.x;
    if (e < E) atomicAdd(&deg[dst[e]], 1);
}

__global__ void inv_sqrt_kernel(const int* __restrict__ deg, float* __restrict__ inv, int n) {
    int i = blockIdx.x * blockDim.x + threadIdx.x;
    if (i < n) inv[i] = rsqrtf(fmaxf((float)deg[i], 1.0f));
}

// ---------------- multi-block exclusive scan ----------------

__global__ void scan_p1(const int* __restrict__ deg, int* __restrict__ bsum, int n) {
    int t = threadIdx.x;                    // 256 threads
    int base = blockIdx.x * 1024 + t * 4;
    int4 v = make_int4(0, 0, 0, 0);
    if (base + 3 < n) v = *(const int4*)(deg + base);
    else {
        if (base + 0 < n) v.x = deg[base + 0];
        if (base + 1 < n) v.y = deg[base + 1];
        if (base + 2 < n) v.z = deg[base + 2];
    }
    int s = v.x + v.y + v.z + v.w;
    #pragma unroll
    for (int off = 32; off > 0; off >>= 1) s += __shfl_xor(s, off);
    __shared__ int wpart[4];
    if ((t & 63) == 0) wpart[t >> 6] = s;
    __syncthreads();
    if (t == 0) bsum[blockIdx.x] = wpart[0] + wpart[1] + wpart[2] + wpart[3];
}

__global__ void scan_p2(int* __restrict__ bsum, int nb, int* __restrict__ rowptr, int n) {
    int t = threadIdx.x;                    // 64 threads, nb <= 64
    int v = (t < nb) ? bsum[t] : 0;
    int sc = v;
    #pragma unroll
    for (int off = 1; off < 64; off <<= 1) {
        int u = __shfl_up(sc, off);
        if (t >= off) sc += u;
    }
    if (t < nb) bsum[t] = sc - v;           // exclusive block offsets
    if (t == 63) rowptr[n] = sc;            // grand total
}

__global__ void scan_p3(const int* __restrict__ deg, const int* __restrict__ bsum,
                        int* __restrict__ rowptr, int* __restrict__ cursor, int n) {
    int t = threadIdx.x;                    // 256 threads
    int base = blockIdx.x * 1024 + t * 4;
    int4 v = make_int4(0, 0, 0, 0);
    if (base + 3 < n) v = *(const int4*)(deg + base);
    else {
        if (base + 0 < n) v.x = deg[base + 0];
        if (base + 1 < n) v.y = deg[base + 1];
        if (base + 2 < n) v.z = deg[base + 2];
    }
    int s = v.x + v.y + v.z + v.w;
    int lane = t & 63;
    int sc = s;
    #pragma unroll
    for (int off = 1; off < 64; off <<= 1) {
        int u = __shfl_up(sc, off);
        if (lane >= off) sc += u;
    }
    __shared__ int wpart[4], woff[4];
    if (lane == 63) wpart[t >> 6] = sc;
    __syncthreads();
    if (t == 0) { int a = 0; for (int i = 0; i < 4; ++i) { woff[i] = a; a += wpart[i]; } }
    __syncthreads();
    int run = bsum[blockIdx.x] + woff[t >> 6] + (sc - s);
    if (base + 0 < n) { rowptr[base + 0] = run; cursor[base + 0] = run; run += v.x; }
    if (base + 1 < n) { rowptr[base + 1] = run; cursor[base + 1] = run; run += v.y; }
    if (base + 2 < n) { rowptr[base + 2] = run; cursor[base + 2] = run; run += v.z; }
    if (base + 3 < n) { rowptr[base + 3] = run; cursor[base + 3] = run; run += v.w; }
}

// ---------------- bucket edges by dst (counting sort fill) ----------------

__global__ void fill_kernel(const int* __restrict__ src, const int* __restrict__ dst,
                            const float* __restrict__ inv, int* __restrict__ cursor,
                            int* __restrict__ src_s, float* __restrict__ norm_s, int E) {
    int e = blockIdx.x * blockDim.x + threadIdx.x;
    if (e >= E) return;
    int s = src[e];
    int d = dst[e];
    int pos = atomicAdd(&cursor[d], 1);
    src_s[pos] = s;
    norm_s[pos] = inv[s] * inv[d];
}

// ---------------- gather aggregation: one wave per node, 2x unrolled ----------------

template<int F>
__global__ void gather_agg_kernel(const float* __restrict__ x, const int* __restrict__ rowptr,
                                  const int* __restrict__ src_s, const float* __restrict__ norm_s,
                                  float* __restrict__ agg) {
    int node = blockIdx.x * 4 + (threadIdx.x >> 6);
    if (node >= N_NODES) return;
    int lane = threadIdx.x & 63;
    int beg = rowptr[node];
    int end = rowptr[node + 1];

    if constexpr (F == 128) {
        float2 acc = {0.0f, 0.0f};
        int p = beg;
        for (; p + 2 <= end; p += 2) {
            int s0 = src_s[p], s1 = src_s[p + 1];
            float n0 = norm_s[p], n1 = norm_s[p + 1];
            float2 v0 = ((const float2*)(x + (size_t)s0 * F))[lane];
            float2 v1 = ((const float2*)(x + (size_t)s1 * F))[lane];
            acc.x = fmaf(v0.x, n0, acc.x);
            acc.y = fmaf(v0.y, n0, acc.y);
            acc.x = fmaf(v1.x, n1, acc.x);
            acc.y = fmaf(v1.y, n1, acc.y);
        }
        if (p < end) {
            int s0 = src_s[p];
            float n0 = norm_s[p];
            float2 v0 = ((const float2*)(x + (size_t)s0 * F))[lane];
            acc.x = fmaf(v0.x, n0, acc.x);
            acc.y = fmaf(v0.y, n0, acc.y);
        }
        ((float2*)(agg + (size_t)node * F))[lane] = acc;
    } else {
        float4 acc = {0.0f, 0.0f, 0.0f, 0.0f};
        int p = beg;
        for (; p + 2 <= end; p += 2) {
            int s0 = src_s[p], s1 = src_s[p + 1];
            float n0 = norm_s[p], n1 = norm_s[p + 1];
            float4 v0 = ((const float4*)(x + (size_t)s0 * F))[lane];
            float4 v1 = ((const float4*)(x + (size_t)s1 * F))[lane];
            acc.x = fmaf(v0.x, n0, acc.x);
            acc.y = fmaf(v0.y, n0, acc.y);
            acc.z = fmaf(v0.z, n0, acc.z);
            acc.w = fmaf(v0.w, n0, acc.w);
            acc.x = fmaf(v1.x, n1, acc.x);
            acc.y = fmaf(v1.y, n1, acc.y);
            acc.z = fmaf(v1.z, n1, acc.z);
            acc.w = fmaf(v1.w, n1, acc.w);
        }
        if (p < end) {
            int s0 = src_s[p];
            float n0 = norm_s[p];
            float4 v0 = ((const float4*)(x + (size_t)s0 * F))[lane];
            acc.x = fmaf(v0.x, n0, acc.x);
            acc.y = fmaf(v0.y, n0, acc.y);
            acc.z = fmaf(v0.z, n0, acc.z);
            acc.w = fmaf(v0.w, n0, acc.w);
        }
        ((float4*)(agg + (size_t)node * F))[lane] = acc;
    }
}

// ---------------- register-tiled GEMM + bias + ReLU (single-buffer, padded) ----------------
// C[M,256] = relu(A[M,K] @ W[K,256] + b). Block tile 128x128, thread tile 8x8,
// BK=16. As padded to stride 132: transpose-staging writes 2-way (free).

template<int K>
__global__ __launch_bounds__(256) void gemm_rt_kernel(const float* __restrict__ A,
                                                      const float* __restrict__ W,
                                                      const float* __restrict__ b,
                                                      float* __restrict__ out, int M) {
    constexpr int BM = 128, BN = 128, BK = 16;
    constexpr int LDA = BM + 4;   // 132
    __shared__ float As[BK][LDA];
    __shared__ float Bs[BK][BN];

    int tid = threadIdx.x;
    int tx = tid & 15;
    int ty = tid >> 4;
    int row0 = blockIdx.x * BM;
    int col0 = blockIdx.y * BN;

    float acc[8][8];
    #pragma unroll
    for (int i = 0; i < 8; ++i)
        #pragma unroll
        for (int j = 0; j < 8; ++j) acc[i][j] = 0.0f;

    for (int kk = 0; kk < K; kk += BK) {
        // stage A tile (BM x BK), transposed into As[k][m]
        #pragma unroll
        for (int i = 0; i < 2; ++i) {
            int f = tid + i * 256;     // 0..511
            int r = f >> 2;            // 0..127
            int c4 = (f & 3) << 2;     // 0,4,8,12
            int row = row0 + r;
            float4 v = (row < M) ? *(const float4*)(A + (size_t)row * K + kk + c4)
                                 : make_float4(0.f, 0.f, 0.f, 0.f);
            As[c4 + 0][r] = v.x;
            As[c4 + 1][r] = v.y;
            As[c4 + 2][r] = v.z;
            As[c4 + 3][r] = v.w;
        }
        // stage B tile (BK x BN)
        #pragma unroll
        for (int i = 0; i < 2; ++i) {
            int f = tid + i * 256;
            int r = f >> 5;            // 0..15
            int c4 = (f & 31) << 2;    // 0..124
            *(float4*)&Bs[r][c4] = *(const float4*)(W + (size_t)(kk + r) * 256 + col0 + c4);
        }
        __syncthreads();

        #pragma unroll
        for (int k = 0; k < BK; ++k) {
            float a[8], bb[8];
            *(float4*)&a[0]  = *(float4*)&As[k][ty * 4];
            *(float4*)&a[4]  = *(float4*)&As[k][64 + ty * 4];
            *(float4*)&bb[0] = *(float4*)&Bs[k][tx * 4];
            *(float4*)&bb[4] = *(float4*)&Bs[k][64 + tx * 4];
            #pragma unroll
            for (int i = 0; i < 8; ++i)
                #pragma unroll
                for (int j = 0; j < 8; ++j)
                    acc[i][j] = fmaf(a[i], bb[j], acc[i][j]);
        }
        __syncthreads();
    }

    // epilogue: bias + relu, guarded stores
    float4 blo = *(const float4*)(b + col0 + tx * 4);
    float4 bhi = *(const float4*)(b + col0 + 64 + tx * 4);
    #pragma unroll
    for (int i = 0; i < 8; ++i) {
        int row = row0 + (i < 4 ? ty * 4 + i : 64 + ty * 4 + (i - 4));
        if (row >= M) continue;
        float* orow = out + (size_t)row * 256 + col0;
        float4 lo, hi;
        lo.x = fmaxf(acc[i][0] + blo.x, 0.f);
        lo.y = fmaxf(acc[i][1] + blo.y, 0.f);
        lo.z = fmaxf(acc[i][2] + blo.z, 0.f);
        lo.w = fmaxf(acc[i][3] + blo.w, 0.f);
        hi.x = fmaxf(acc[i][4] + bhi.x, 0.f);
        hi.y = fmaxf(acc[i][5] + bhi.y, 0.f);
        hi.z = fmaxf(acc[i][6] + bhi.z, 0.f);
        hi.w = fmaxf(acc[i][7] + bhi.w, 0.f);
        *(float4*)(orow + tx * 4) = lo;
        *(float4*)(orow + 64 + tx * 4) = hi;
    }
}

// ---------------- dense head + softmax, LDS-staged ----------------
// 32 rows/block, 256 threads: thread = (row r = tid>>3, colgroup cg = tid&7 -> 5 cols).
// Wd staged transposed in LDS once per block; h rows staged in LDS.
// logits -> 8-lane shfl softmax -> out. LDS = 32*260*4 + 40*260*4 = 74.9 KB.

__global__ __launch_bounds__(256) void dense_softmax_kernel(const float* __restrict__ h,
                                                            const float* __restrict__ Wd,
                                                            const float* __restrict__ bd,
                                                            float* __restrict__ out, int M) {
    __shared__ float hs[32][260];
    __shared__ float wt[40][260];
    int tid = threadIdx.x;
    int row0 = blockIdx.x * 32;

    // stage Wd [256][40] -> wt[c][k]
    for (int i = tid; i < 40 * 256; i += 256) {
        int k = i / 40;
        int c = i - k * 40;
        wt[c][k] = Wd[i];
    }
    // stage 32 h-rows (guarded; rows >= M stay garbage and are never stored)
    #pragma unroll
    for (int i = 0; i < 8; ++i) {
        int f = tid + i * 256;       // 0..2047
        int r = f >> 6;              // 0..31
        int k4 = (f & 63) << 2;      // 0..252
        float4 v = make_float4(0.f, 0.f, 0.f, 0.f);
        if (row0 + r < M) v = *(const float4*)(h + (size_t)(row0 + r) * 256 + k4);
        *(float4*)&hs[r][k4] = v;
    }
    __syncthreads();

    int r  = tid >> 3;   // 0..31
    int cg = tid & 7;    // 0..7 -> cols cg*5..cg*5+4
    int c0 = cg * 5;

    float acc[5] = {0.f, 0.f, 0.f, 0.f, 0.f};
    #pragma unroll 4
    for (int k4 = 0; k4 < 64; ++k4) {
        float4 hv = *(float4*)&hs[r][k4 * 4];
        #pragma unroll
        for (int j = 0; j < 5; ++j) {
            float4 wv = *(float4*)&wt[c0 + j][k4 * 4];
            acc[j] = fmaf(hv.x, wv.x, acc[j]);
            acc[j] = fmaf(hv.y, wv.y, acc[j]);
            acc[j] = fmaf(hv.z, wv.z, acc[j]);
            acc[j] = fmaf(hv.w, wv.w, acc[j]);
        }
    }
    #pragma unroll
    for (int j = 0; j < 5; ++j) acc[j] += bd[c0 + j];

    // softmax across the 8 lanes of this row (lanes r*8 .. r*8+7)
    float m = acc[0];
    #pragma unroll
    for (int j = 1; j < 5; ++j) m = fmaxf(m, acc[j]);
    #pragma unroll
    for (int off = 1; off < 8; off <<= 1) m = fmaxf(m, __shfl_xor(m, off));

    float e[5], s = 0.f;
    #pragma unroll
    for (int j = 0; j < 5; ++j) { e[j] = expf(acc[j] - m); s += e[j]; }
    #pragma unroll
    for (int off = 1; off < 8; off <<= 1) s += __shfl_xor(s, off);

    int row = row0 + r;
    if (row < M) {
        float inv_s = 1.0f / s;
        float* orow = out + (size_t)row * 40 + c0;
        #pragma unroll
        for (int j = 0; j < 5; ++j) orow[j] = e[j] * inv_s;
    }
}

// ---------------- launch ----------------

extern "C" void kernel_launch(void* const* d_in, const int* in_sizes, int n_in,
                              void* d_out, int out_size, void* d_ws, size_t ws_size,
                              hipStream_t stream) {
    const float* x  = (const float*)d_in[0];
    const int*   ei = (const int*)d_in[1];
    const float* W1 = (const float*)d_in[2];
    const float* b1 = (const float*)d_in[3];
    const float* W2 = (const float*)d_in[4];
    const float* b2 = (const float*)d_in[5];
    const float* Wd = (const float*)d_in[6];
    const float* bd = (const float*)d_in[7];
    float* out = (float*)d_out;

    const int N = N_NODES;
    const int E = in_sizes[1] / 2;
    const int* src = ei;
    const int* dst = ei + E;

    // workspace layout (bytes, 1KB-aligned). Total ~108 MB.
    char* ws = (char*)d_ws;
    size_t off = 0;
    auto alloc = [&](size_t bytes) { char* p = ws + off; off += (bytes + 1023) & ~(size_t)1023; return p; };
    int*   deg    = (int*)alloc((size_t)N * 4);
    float* inv    = (float*)alloc((size_t)N * 4);
    int*   rowptr = (int*)alloc((size_t)(N + 1) * 4);
    int*   cursor = (int*)alloc((size_t)N * 4);
    int*   bsum   = (int*)alloc((size_t)64 * 4);
    int*   src_s  = (int*)alloc((size_t)E * 4);
    float* norm_s = (float*)alloc((size_t)E * 4);
    float* h1     = (float*)alloc((size_t)N * 256 * 4);
    float* agg2   = (float*)alloc((size_t)N * 256 * 4);
    float* agg1   = agg2;   // agg1 [N,128] aliases agg2 region (lifetimes disjoint)
    float* h2     = h1;     // h2 reuses h1

    hipMemsetAsync(deg, 0, (size_t)N * 4, stream);

    const int nb = (N + 1023) / 1024;   // 49 scan blocks

    // degree -> inv_sqrt -> rowptr(+cursor) -> bucketed (src_s, norm_s)
    deg_kernel<<<(E + 255) / 256, 256, 0, stream>>>(dst, deg, E);
    inv_sqrt_kernel<<<(N + 255) / 256, 256, 0, stream>>>(deg, inv, N);
    scan_p1<<<nb, 256, 0, stream>>>(deg, bsum, N);
    scan_p2<<<1, 64, 0, stream>>>(bsum, nb, rowptr, N);
    scan_p3<<<nb, 256, 0, stream>>>(deg, bsum, rowptr, cursor, N);
    fill_kernel<<<(E + 255) / 256, 256, 0, stream>>>(src, dst, inv, cursor, src_s, norm_s, E);

    // conv1: gather-aggregate into agg1 [N,128], then h1 = relu(agg1@W1 + b1)
    gather_agg_kernel<128><<<(N + 3) / 4, 256, 0, stream>>>(x, rowptr, src_s, norm_s, agg1);
    {
        dim3 grid((N + 127) / 128, 2);
        gemm_rt_kernel<128><<<grid, 256, 0, stream>>>(agg1, W1, b1, h1, N);
    }

    // conv2: gather-aggregate h1 into agg2 [N,256], then h2 = relu(agg2@W2 + b2)
    gather_agg_kernel<256><<<(N + 3) / 4, 256, 0, stream>>>(h1, rowptr, src_s, norm_s, agg2);
    {
        dim3 grid((N + 127) / 128, 2);
        gemm_rt_kernel<256><<<grid, 256, 0, stream>>>(agg2, W2, b2, h2, N);
    }

    // dense + softmax (LDS-staged)
    dense_softmax_kernel<<<(N + 31) / 32, 256, 0, stream>>>(h2, Wd, bd, out, N);
}

// Round 6
// 375.125 us; speedup vs baseline: 1.6355x; 1.0956x over previous
//
#include <hip/hip_runtime.h>
#include <hip/hip_bf16.h>
#include <math.h>

#define N_NODES 50000

typedef short short8 __attribute__((ext_vector_type(8)));
typedef float f32x4 __attribute__((ext_vector_type(4)));

// RNE split of f32 into bf16 hi + bf16 lo (a ~= hi + lo, rel err ~2^-18)
static __device__ __forceinline__ void split2(float x, unsigned short& hi, unsigned short& lo) {
    unsigned u = __builtin_bit_cast(unsigned, x);
    unsigned r = u + 0x7FFF + ((u >> 16) & 1);
    hi = (unsigned short)(r >> 16);
    float hf = __builtin_bit_cast(float, (unsigned)hi << 16);
    float res = x - hf;
    unsigned v = __builtin_bit_cast(unsigned, res);
    unsigned r2 = v + 0x7FFF + ((v >> 16) & 1);
    lo = (unsigned short)(r2 >> 16);
}

// ---------------- degree (int histogram) ----------------

__global__ void deg_kernel(const int* __restrict__ dst, int* __restrict__ deg, int E) {
    int e = blockIdx.x * blockDim.x + threadIdx.x;
    if (e < E) atomicAdd(&deg[dst[e]], 1);
}

__global__ void inv_sqrt_kernel(const int* __restrict__ deg, float* __restrict__ inv, int n) {
    int i = blockIdx.x * blockDim.x + threadIdx.x;
    if (i < n) inv[i] = rsqrtf(fmaxf((float)deg[i], 1.0f));
}

// ---------------- multi-block exclusive scan ----------------

__global__ void scan_p1(const int* __restrict__ deg, int* __restrict__ bsum, int n) {
    int t = threadIdx.x;                    // 256 threads
    int base = blockIdx.x * 1024 + t * 4;
    int4 v = make_int4(0, 0, 0, 0);
    if (base + 3 < n) v = *(const int4*)(deg + base);
    else {
        if (base + 0 < n) v.x = deg[base + 0];
        if (base + 1 < n) v.y = deg[base + 1];
        if (base + 2 < n) v.z = deg[base + 2];
    }
    int s = v.x + v.y + v.z + v.w;
    #pragma unroll
    for (int off = 32; off > 0; off >>= 1) s += __shfl_xor(s, off);
    __shared__ int wpart[4];
    if ((t & 63) == 0) wpart[t >> 6] = s;
    __syncthreads();
    if (t == 0) bsum[blockIdx.x] = wpart[0] + wpart[1] + wpart[2] + wpart[3];
}

__global__ void scan_p2(int* __restrict__ bsum, int nb, int* __restrict__ rowptr, int n) {
    int t = threadIdx.x;                    // 64 threads, nb <= 64
    int v = (t < nb) ? bsum[t] : 0;
    int sc = v;
    #pragma unroll
    for (int off = 1; off < 64; off <<= 1) {
        int u = __shfl_up(sc, off);
        if (t >= off) sc += u;
    }
    if (t < nb) bsum[t] = sc - v;           // exclusive block offsets
    if (t == 63) rowptr[n] = sc;            // grand total
}

__global__ void scan_p3(const int* __restrict__ deg, const int* __restrict__ bsum,
                        int* __restrict__ rowptr, int* __restrict__ cursor, int n) {
    int t = threadIdx.x;                    // 256 threads
    int base = blockIdx.x * 1024 + t * 4;
    int4 v = make_int4(0, 0, 0, 0);
    if (base + 3 < n) v = *(const int4*)(deg + base);
    else {
        if (base + 0 < n) v.x = deg[base + 0];
        if (base + 1 < n) v.y = deg[base + 1];
        if (base + 2 < n) v.z = deg[base + 2];
    }
    int s = v.x + v.y + v.z + v.w;
    int lane = t & 63;
    int sc = s;
    #pragma unroll
    for (int off = 1; off < 64; off <<= 1) {
        int u = __shfl_up(sc, off);
        if (lane >= off) sc += u;
    }
    __shared__ int wpart[4], woff[4];
    if (lane == 63) wpart[t >> 6] = sc;
    __syncthreads();
    if (t == 0) { int a = 0; for (int i = 0; i < 4; ++i) { woff[i] = a; a += wpart[i]; } }
    __syncthreads();
    int run = bsum[blockIdx.x] + woff[t >> 6] + (sc - s);
    if (base + 0 < n) { rowptr[base + 0] = run; cursor[base + 0] = run; run += v.x; }
    if (base + 1 < n) { rowptr[base + 1] = run; cursor[base + 1] = run; run += v.y; }
    if (base + 2 < n) { rowptr[base + 2] = run; cursor[base + 2] = run; run += v.z; }
    if (base + 3 < n) { rowptr[base + 3] = run; cursor[base + 3] = run; run += v.w; }
}

// ---------------- bucket edges by dst (counting sort fill) ----------------

__global__ void fill_kernel(const int* __restrict__ src, const int* __restrict__ dst,
                            const float* __restrict__ inv, int* __restrict__ cursor,
                            int* __restrict__ src_s, float* __restrict__ norm_s, int E) {
    int e = blockIdx.x * blockDim.x + threadIdx.x;
    if (e >= E) return;
    int s = src[e];
    int d = dst[e];
    int pos = atomicAdd(&cursor[d], 1);
    src_s[pos] = s;
    norm_s[pos] = inv[s] * inv[d];
}

// ---------------- gather aggregation: one wave per node, writes split bf16 ----------------

template<int F>
__global__ void gather_agg_kernel(const float* __restrict__ x, const int* __restrict__ rowptr,
                                  const int* __restrict__ src_s, const float* __restrict__ norm_s,
                                  unsigned short* __restrict__ agg_hi,
                                  unsigned short* __restrict__ agg_lo) {
    int node = blockIdx.x * 4 + (threadIdx.x >> 6);
    if (node >= N_NODES) return;
    int lane = threadIdx.x & 63;
    int beg = rowptr[node];
    int end = rowptr[node + 1];

    if constexpr (F == 128) {
        float2 acc = {0.0f, 0.0f};
        int p = beg;
        for (; p + 2 <= end; p += 2) {
            int s0 = src_s[p], s1 = src_s[p + 1];
            float n0 = norm_s[p], n1 = norm_s[p + 1];
            float2 v0 = ((const float2*)(x + (size_t)s0 * F))[lane];
            float2 v1 = ((const float2*)(x + (size_t)s1 * F))[lane];
            acc.x = fmaf(v0.x, n0, acc.x);
            acc.y = fmaf(v0.y, n0, acc.y);
            acc.x = fmaf(v1.x, n1, acc.x);
            acc.y = fmaf(v1.y, n1, acc.y);
        }
        if (p < end) {
            int s0 = src_s[p];
            float n0 = norm_s[p];
            float2 v0 = ((const float2*)(x + (size_t)s0 * F))[lane];
            acc.x = fmaf(v0.x, n0, acc.x);
            acc.y = fmaf(v0.y, n0, acc.y);
        }
        unsigned short h0, l0, h1, l1;
        split2(acc.x, h0, l0);
        split2(acc.y, h1, l1);
        ((ushort2*)(agg_hi + (size_t)node * F))[lane] = make_ushort2(h0, h1);
        ((ushort2*)(agg_lo + (size_t)node * F))[lane] = make_ushort2(l0, l1);
    } else {
        float4 acc = {0.0f, 0.0f, 0.0f, 0.0f};
        int p = beg;
        for (; p + 2 <= end; p += 2) {
            int s0 = src_s[p], s1 = src_s[p + 1];
            float n0 = norm_s[p], n1 = norm_s[p + 1];
            float4 v0 = ((const float4*)(x + (size_t)s0 * F))[lane];
            float4 v1 = ((const float4*)(x + (size_t)s1 * F))[lane];
            acc.x = fmaf(v0.x, n0, acc.x);
            acc.y = fmaf(v0.y, n0, acc.y);
            acc.z = fmaf(v0.z, n0, acc.z);
            acc.w = fmaf(v0.w, n0, acc.w);
            acc.x = fmaf(v1.x, n1, acc.x);
            acc.y = fmaf(v1.y, n1, acc.y);
            acc.z = fmaf(v1.z, n1, acc.z);
            acc.w = fmaf(v1.w, n1, acc.w);
        }
        if (p < end) {
            int s0 = src_s[p];
            float n0 = norm_s[p];
            float4 v0 = ((const float4*)(x + (size_t)s0 * F))[lane];
            acc.x = fmaf(v0.x, n0, acc.x);
            acc.y = fmaf(v0.y, n0, acc.y);
            acc.z = fmaf(v0.z, n0, acc.z);
            acc.w = fmaf(v0.w, n0, acc.w);
        }
        unsigned short h0, l0, h1, l1, h2, l2, h3, l3;
        split2(acc.x, h0, l0);
        split2(acc.y, h1, l1);
        split2(acc.z, h2, l2);
        split2(acc.w, h3, l3);
        ((ushort4*)(agg_hi + (size_t)node * F))[lane] = make_ushort4(h0, h1, h2, h3);
        ((ushort4*)(agg_lo + (size_t)node * F))[lane] = make_ushort4(l0, l1, l2, l3);
    }
}

// ---------------- W split + transpose: W[K][256] f32 -> Bt_hi/lo [256][K] bf16 ----------------

__global__ void split_w_kernel(const float* __restrict__ W, unsigned short* __restrict__ bhi,
                               unsigned short* __restrict__ blo, int K) {
    int i = blockIdx.x * 256 + threadIdx.x;
    if (i >= K * 256) return;
    int k = i >> 8;
    int n = i & 255;
    unsigned short h, l;
    split2(W[i], h, l);
    bhi[(size_t)n * K + k] = h;
    blo[(size_t)n * K + k] = l;
}

// ---------------- MFMA GEMM (split bf16, 3 products) + bias + ReLU ----------------
// out[M,256] = relu(A[M,K] @ W[K,256] + b). A given as hi/lo bf16 [M][K] (row-major),
// W as hi/lo bf16 [256][K] (transposed). 256 thr = 4 waves; wave w owns cols [64w,64w+64).
// All fragments loaded straight from global (L2-hot); no LDS, no barriers.
// mfma_f32_16x16x32_bf16: A-frag lane l: row=l&15, k=(l>>4)*8+j; B symmetric;
// C/D: col=lane&15, row=(lane>>4)*4+reg.

template<int K, bool RELU>
__global__ __launch_bounds__(256) void gemm_mfma_kernel(
    const unsigned short* __restrict__ Ahi, const unsigned short* __restrict__ Alo,
    const unsigned short* __restrict__ Bhi, const unsigned short* __restrict__ Blo,
    const float* __restrict__ bias, float* __restrict__ out, int M)
{
    int lane = threadIdx.x & 63;
    int wave = threadIdx.x >> 6;
    int row0 = blockIdx.x * 64;
    int col0 = wave * 64;
    int lr = lane & 15;
    int koff0 = (lane >> 4) * 8;

    f32x4 acc[4][4];
    #pragma unroll
    for (int i = 0; i < 4; ++i)
        #pragma unroll
        for (int j = 0; j < 4; ++j) acc[i][j] = (f32x4){0.f, 0.f, 0.f, 0.f};

    #pragma unroll 1
    for (int kk = 0; kk < K; kk += 32) {
        int ko = kk + koff0;
        short8 ah[4], al[4], bh[4], bl[4];
        #pragma unroll
        for (int t = 0; t < 4; ++t) {
            size_t aoff = (size_t)(row0 + t * 16 + lr) * K + ko;
            ah[t] = *(const short8*)(Ahi + aoff);
            al[t] = *(const short8*)(Alo + aoff);
            size_t boff = (size_t)(col0 + t * 16 + lr) * K + ko;
            bh[t] = *(const short8*)(Bhi + boff);
            bl[t] = *(const short8*)(Blo + boff);
        }
        #pragma unroll
        for (int mt = 0; mt < 4; ++mt)
            #pragma unroll
            for (int nt = 0; nt < 4; ++nt) {
                acc[mt][nt] = __builtin_amdgcn_mfma_f32_16x16x32_bf16(ah[mt], bh[nt], acc[mt][nt], 0, 0, 0);
                acc[mt][nt] = __builtin_amdgcn_mfma_f32_16x16x32_bf16(ah[mt], bl[nt], acc[mt][nt], 0, 0, 0);
                acc[mt][nt] = __builtin_amdgcn_mfma_f32_16x16x32_bf16(al[mt], bh[nt], acc[mt][nt], 0, 0, 0);
            }
    }

    int rgrp = (lane >> 4) * 4;
    #pragma unroll
    for (int mt = 0; mt < 4; ++mt) {
        #pragma unroll
        for (int nt = 0; nt < 4; ++nt) {
            int c = col0 + nt * 16 + lr;
            float bv = bias[c];
            #pragma unroll
            for (int reg = 0; reg < 4; ++reg) {
                int r = row0 + mt * 16 + rgrp + reg;
                if (r < M) {
                    float v = acc[mt][nt][reg] + bv;
                    if (RELU) v = fmaxf(v, 0.0f);
                    out[(size_t)r * 256 + c] = v;
                }
            }
        }
    }
}

// ---------------- dense head + softmax, LDS-staged ----------------

__global__ __launch_bounds__(256) void dense_softmax_kernel(const float* __restrict__ h,
                                                            const float* __restrict__ Wd,
                                                            const float* __restrict__ bd,
                                                            float* __restrict__ out, int M) {
    __shared__ float hs[32][260];
    __shared__ float wt[40][260];
    int tid = threadIdx.x;
    int row0 = blockIdx.x * 32;

    for (int i = tid; i < 40 * 256; i += 256) {
        int k = i / 40;
        int c = i - k * 40;
        wt[c][k] = Wd[i];
    }
    #pragma unroll
    for (int i = 0; i < 8; ++i) {
        int f = tid + i * 256;
        int r = f >> 6;
        int k4 = (f & 63) << 2;
        float4 v = make_float4(0.f, 0.f, 0.f, 0.f);
        if (row0 + r < M) v = *(const float4*)(h + (size_t)(row0 + r) * 256 + k4);
        *(float4*)&hs[r][k4] = v;
    }
    __syncthreads();

    int r  = tid >> 3;
    int cg = tid & 7;
    int c0 = cg * 5;

    float acc[5] = {0.f, 0.f, 0.f, 0.f, 0.f};
    #pragma unroll 4
    for (int k4 = 0; k4 < 64; ++k4) {
        float4 hv = *(float4*)&hs[r][k4 * 4];
        #pragma unroll
        for (int j = 0; j < 5; ++j) {
            float4 wv = *(float4*)&wt[c0 + j][k4 * 4];
            acc[j] = fmaf(hv.x, wv.x, acc[j]);
            acc[j] = fmaf(hv.y, wv.y, acc[j]);
            acc[j] = fmaf(hv.z, wv.z, acc[j]);
            acc[j] = fmaf(hv.w, wv.w, acc[j]);
        }
    }
    #pragma unroll
    for (int j = 0; j < 5; ++j) acc[j] += bd[c0 + j];

    float m = acc[0];
    #pragma unroll
    for (int j = 1; j < 5; ++j) m = fmaxf(m, acc[j]);
    #pragma unroll
    for (int off = 1; off < 8; off <<= 1) m = fmaxf(m, __shfl_xor(m, off));

    float e[5], s = 0.f;
    #pragma unroll
    for (int j = 0; j < 5; ++j) { e[j] = expf(acc[j] - m); s += e[j]; }
    #pragma unroll
    for (int off = 1; off < 8; off <<= 1) s += __shfl_xor(s, off);

    int row = row0 + r;
    if (row < M) {
        float inv_s = 1.0f / s;
        float* orow = out + (size_t)row * 40 + c0;
        #pragma unroll
        for (int j = 0; j < 5; ++j) orow[j] = e[j] * inv_s;
    }
}

// ---------------- launch ----------------

extern "C" void kernel_launch(void* const* d_in, const int* in_sizes, int n_in,
                              void* d_out, int out_size, void* d_ws, size_t ws_size,
                              hipStream_t stream) {
    const float* x  = (const float*)d_in[0];
    const int*   ei = (const int*)d_in[1];
    const float* W1 = (const float*)d_in[2];
    const float* b1 = (const float*)d_in[3];
    const float* W2 = (const float*)d_in[4];
    const float* b2 = (const float*)d_in[5];
    const float* Wd = (const float*)d_in[6];
    const float* bd = (const float*)d_in[7];
    float* out = (float*)d_out;

    const int N = N_NODES;
    const int E = in_sizes[1] / 2;
    const int* src = ei;
    const int* dst = ei + E;

    const int MP = 50048;   // M padded to multiple of 64 for MFMA tiles

    // workspace layout (bytes, 1KB-aligned). ~110 MB.
    char* ws = (char*)d_ws;
    size_t off = 0;
    auto alloc = [&](size_t bytes) { char* p = ws + off; off += (bytes + 1023) & ~(size_t)1023; return p; };
    int*   deg    = (int*)alloc((size_t)N * 4);
    float* inv    = (float*)alloc((size_t)N * 4);
    int*   rowptr = (int*)alloc((size_t)(N + 1) * 4);
    int*   cursor = (int*)alloc((size_t)N * 4);
    int*   bsum   = (int*)alloc((size_t)64 * 4);
    int*   src_s  = (int*)alloc((size_t)E * 4);
    float* norm_s = (float*)alloc((size_t)E * 4);
    float* h1     = (float*)alloc((size_t)N * 256 * 4);                    // h1 / h2 (f32)
    unsigned short* aggU = (unsigned short*)alloc((size_t)MP * 256 * 2 * 2); // union region
    unsigned short* w1hi = (unsigned short*)alloc((size_t)128 * 256 * 2);
    unsigned short* w1lo = (unsigned short*)alloc((size_t)128 * 256 * 2);
    unsigned short* w2hi = (unsigned short*)alloc((size_t)256 * 256 * 2);
    unsigned short* w2lo = (unsigned short*)alloc((size_t)256 * 256 * 2);

    // union aliases: agg1 (K=128) uses first half; agg2 (K=256) uses whole region
    unsigned short* agg1_hi = aggU;
    unsigned short* agg1_lo = aggU + (size_t)MP * 128;
    unsigned short* agg2_hi = aggU;
    unsigned short* agg2_lo = aggU + (size_t)MP * 256;
    float* h2 = h1;

    hipMemsetAsync(deg, 0, (size_t)N * 4, stream);

    const int nb = (N + 1023) / 1024;   // 49 scan blocks

    // degree -> inv_sqrt -> rowptr(+cursor) -> bucketed (src_s, norm_s)
    deg_kernel<<<(E + 255) / 256, 256, 0, stream>>>(dst, deg, E);
    inv_sqrt_kernel<<<(N + 255) / 256, 256, 0, stream>>>(deg, inv, N);
    scan_p1<<<nb, 256, 0, stream>>>(deg, bsum, N);
    scan_p2<<<1, 64, 0, stream>>>(bsum, nb, rowptr, N);
    scan_p3<<<nb, 256, 0, stream>>>(deg, bsum, rowptr, cursor, N);
    fill_kernel<<<(E + 255) / 256, 256, 0, stream>>>(src, dst, inv, cursor, src_s, norm_s, E);

    // pre-split weights (transposed)
    split_w_kernel<<<(128 * 256 + 255) / 256, 256, 0, stream>>>(W1, w1hi, w1lo, 128);
    split_w_kernel<<<(256 * 256 + 255) / 256, 256, 0, stream>>>(W2, w2hi, w2lo, 256);

    // conv1: gather into agg1 (split bf16), then h1 = relu(agg1 @ W1 + b1) via MFMA
    gather_agg_kernel<128><<<(N + 3) / 4, 256, 0, stream>>>(x, rowptr, src_s, norm_s, agg1_hi, agg1_lo);
    gemm_mfma_kernel<128, true><<<MP / 64, 256, 0, stream>>>(agg1_hi, agg1_lo, w1hi, w1lo, b1, h1, N);

    // conv2: gather h1 into agg2 (split bf16), then h2 = relu(agg2 @ W2 + b2) via MFMA
    gather_agg_kernel<256><<<(N + 3) / 4, 256, 0, stream>>>(h1, rowptr, src_s, norm_s, agg2_hi, agg2_lo);
    gemm_mfma_kernel<256, true><<<MP / 64, 256, 0, stream>>>(agg2_hi, agg2_lo, w2hi, w2lo, b2, h2, N);

    // dense + softmax (LDS-staged)
    dense_softmax_kernel<<<(N + 31) / 32, 256, 0, stream>>>(h2, Wd, bd, out, N);
}

// Round 7
// 373.130 us; speedup vs baseline: 1.6442x; 1.0053x over previous
//
#include <hip/hip_runtime.h>
#include <hip/hip_bf16.h>
#include <math.h>

#define N_NODES 50000

typedef short short8 __attribute__((ext_vector_type(8)));
typedef float f32x4 __attribute__((ext_vector_type(4)));

// RNE split of f32 into bf16 hi + bf16 lo (a ~= hi + lo, rel err ~2^-18)
static __device__ __forceinline__ void split2(float x, unsigned short& hi, unsigned short& lo) {
    unsigned u = __builtin_bit_cast(unsigned, x);
    unsigned r = u + 0x7FFF + ((u >> 16) & 1);
    hi = (unsigned short)(r >> 16);
    float hf = __builtin_bit_cast(float, (unsigned)hi << 16);
    float res = x - hf;
    unsigned v = __builtin_bit_cast(unsigned, res);
    unsigned r2 = v + 0x7FFF + ((v >> 16) & 1);
    lo = (unsigned short)(r2 >> 16);
}

// ---------------- degree (int histogram) ----------------

__global__ void deg_kernel(const int* __restrict__ dst, int* __restrict__ deg, int E) {
    int e = blockIdx.x * blockDim.x + threadIdx.x;
    if (e < E) atomicAdd(&deg[dst[e]], 1);
}

__global__ void inv_sqrt_kernel(const int* __restrict__ deg, float* __restrict__ inv, int n) {
    int i = blockIdx.x * blockDim.x + threadIdx.x;
    if (i < n) inv[i] = rsqrtf(fmaxf((float)deg[i], 1.0f));
}

// ---------------- multi-block exclusive scan ----------------

__global__ void scan_p1(const int* __restrict__ deg, int* __restrict__ bsum, int n) {
    int t = threadIdx.x;                    // 256 threads
    int base = blockIdx.x * 1024 + t * 4;
    int4 v = make_int4(0, 0, 0, 0);
    if (base + 3 < n) v = *(const int4*)(deg + base);
    else {
        if (base + 0 < n) v.x = deg[base + 0];
        if (base + 1 < n) v.y = deg[base + 1];
        if (base + 2 < n) v.z = deg[base + 2];
    }
    int s = v.x + v.y + v.z + v.w;
    #pragma unroll
    for (int off = 32; off > 0; off >>= 1) s += __shfl_xor(s, off);
    __shared__ int wpart[4];
    if ((t & 63) == 0) wpart[t >> 6] = s;
    __syncthreads();
    if (t == 0) bsum[blockIdx.x] = wpart[0] + wpart[1] + wpart[2] + wpart[3];
}

__global__ void scan_p2(int* __restrict__ bsum, int nb, int* __restrict__ rowptr, int n) {
    int t = threadIdx.x;                    // 64 threads, nb <= 64
    int v = (t < nb) ? bsum[t] : 0;
    int sc = v;
    #pragma unroll
    for (int off = 1; off < 64; off <<= 1) {
        int u = __shfl_up(sc, off);
        if (t >= off) sc += u;
    }
    if (t < nb) bsum[t] = sc - v;           // exclusive block offsets
    if (t == 63) rowptr[n] = sc;            // grand total
}

__global__ void scan_p3(const int* __restrict__ deg, const int* __restrict__ bsum,
                        int* __restrict__ rowptr, int* __restrict__ cursor, int n) {
    int t = threadIdx.x;                    // 256 threads
    int base = blockIdx.x * 1024 + t * 4;
    int4 v = make_int4(0, 0, 0, 0);
    if (base + 3 < n) v = *(const int4*)(deg + base);
    else {
        if (base + 0 < n) v.x = deg[base + 0];
        if (base + 1 < n) v.y = deg[base + 1];
        if (base + 2 < n) v.z = deg[base + 2];
    }
    int s = v.x + v.y + v.z + v.w;
    int lane = t & 63;
    int sc = s;
    #pragma unroll
    for (int off = 1; off < 64; off <<= 1) {
        int u = __shfl_up(sc, off);
        if (lane >= off) sc += u;
    }
    __shared__ int wpart[4], woff[4];
    if (lane == 63) wpart[t >> 6] = sc;
    __syncthreads();
    if (t == 0) { int a = 0; for (int i = 0; i < 4; ++i) { woff[i] = a; a += wpart[i]; } }
    __syncthreads();
    int run = bsum[blockIdx.x] + woff[t >> 6] + (sc - s);
    if (base + 0 < n) { rowptr[base + 0] = run; cursor[base + 0] = run; run += v.x; }
    if (base + 1 < n) { rowptr[base + 1] = run; cursor[base + 1] = run; run += v.y; }
    if (base + 2 < n) { rowptr[base + 2] = run; cursor[base + 2] = run; run += v.z; }
    if (base + 3 < n) { rowptr[base + 3] = run; cursor[base + 3] = run; run += v.w; }
}

// ---------------- bucket edges by dst (counting sort fill) ----------------

__global__ void fill_kernel(const int* __restrict__ src, const int* __restrict__ dst,
                            const float* __restrict__ inv, int* __restrict__ cursor,
                            int* __restrict__ src_s, float* __restrict__ norm_s, int E) {
    int e = blockIdx.x * blockDim.x + threadIdx.x;
    if (e >= E) return;
    int s = src[e];
    int d = dst[e];
    int pos = atomicAdd(&cursor[d], 1);
    src_s[pos] = s;
    norm_s[pos] = inv[s] * inv[d];
}

// ---------------- gather aggregation: one wave per node, 4x unrolled (MLP) ----------------

template<int F>
__global__ void gather_agg_kernel(const float* __restrict__ x, const int* __restrict__ rowptr,
                                  const int* __restrict__ src_s, const float* __restrict__ norm_s,
                                  unsigned short* __restrict__ agg_hi,
                                  unsigned short* __restrict__ agg_lo) {
    int node = blockIdx.x * 4 + (threadIdx.x >> 6);
    if (node >= N_NODES) return;
    int lane = threadIdx.x & 63;
    int beg = rowptr[node];
    int end = rowptr[node + 1];

    if constexpr (F == 128) {
        float2 acc = {0.0f, 0.0f};
        int p = beg;
        for (; p + 4 <= end; p += 4) {
            int s0 = src_s[p], s1 = src_s[p + 1], s2 = src_s[p + 2], s3 = src_s[p + 3];
            float n0 = norm_s[p], n1 = norm_s[p + 1], n2 = norm_s[p + 2], n3 = norm_s[p + 3];
            float2 v0 = ((const float2*)(x + (size_t)s0 * F))[lane];
            float2 v1 = ((const float2*)(x + (size_t)s1 * F))[lane];
            float2 v2 = ((const float2*)(x + (size_t)s2 * F))[lane];
            float2 v3 = ((const float2*)(x + (size_t)s3 * F))[lane];
            acc.x = fmaf(v0.x, n0, acc.x); acc.y = fmaf(v0.y, n0, acc.y);
            acc.x = fmaf(v1.x, n1, acc.x); acc.y = fmaf(v1.y, n1, acc.y);
            acc.x = fmaf(v2.x, n2, acc.x); acc.y = fmaf(v2.y, n2, acc.y);
            acc.x = fmaf(v3.x, n3, acc.x); acc.y = fmaf(v3.y, n3, acc.y);
        }
        for (; p < end; ++p) {
            int s0 = src_s[p];
            float n0 = norm_s[p];
            float2 v0 = ((const float2*)(x + (size_t)s0 * F))[lane];
            acc.x = fmaf(v0.x, n0, acc.x);
            acc.y = fmaf(v0.y, n0, acc.y);
        }
        unsigned short h0, l0, h1, l1;
        split2(acc.x, h0, l0);
        split2(acc.y, h1, l1);
        ((ushort2*)(agg_hi + (size_t)node * F))[lane] = make_ushort2(h0, h1);
        ((ushort2*)(agg_lo + (size_t)node * F))[lane] = make_ushort2(l0, l1);
    } else {
        float4 acc = {0.0f, 0.0f, 0.0f, 0.0f};
        int p = beg;
        for (; p + 4 <= end; p += 4) {
            int s0 = src_s[p], s1 = src_s[p + 1], s2 = src_s[p + 2], s3 = src_s[p + 3];
            float n0 = norm_s[p], n1 = norm_s[p + 1], n2 = norm_s[p + 2], n3 = norm_s[p + 3];
            float4 v0 = ((const float4*)(x + (size_t)s0 * F))[lane];
            float4 v1 = ((const float4*)(x + (size_t)s1 * F))[lane];
            float4 v2 = ((const float4*)(x + (size_t)s2 * F))[lane];
            float4 v3 = ((const float4*)(x + (size_t)s3 * F))[lane];
            acc.x = fmaf(v0.x, n0, acc.x); acc.y = fmaf(v0.y, n0, acc.y);
            acc.z = fmaf(v0.z, n0, acc.z); acc.w = fmaf(v0.w, n0, acc.w);
            acc.x = fmaf(v1.x, n1, acc.x); acc.y = fmaf(v1.y, n1, acc.y);
            acc.z = fmaf(v1.z, n1, acc.z); acc.w = fmaf(v1.w, n1, acc.w);
            acc.x = fmaf(v2.x, n2, acc.x); acc.y = fmaf(v2.y, n2, acc.y);
            acc.z = fmaf(v2.z, n2, acc.z); acc.w = fmaf(v2.w, n2, acc.w);
            acc.x = fmaf(v3.x, n3, acc.x); acc.y = fmaf(v3.y, n3, acc.y);
            acc.z = fmaf(v3.z, n3, acc.z); acc.w = fmaf(v3.w, n3, acc.w);
        }
        for (; p < end; ++p) {
            int s0 = src_s[p];
            float n0 = norm_s[p];
            float4 v0 = ((const float4*)(x + (size_t)s0 * F))[lane];
            acc.x = fmaf(v0.x, n0, acc.x);
            acc.y = fmaf(v0.y, n0, acc.y);
            acc.z = fmaf(v0.z, n0, acc.z);
            acc.w = fmaf(v0.w, n0, acc.w);
        }
        unsigned short h0, l0, h1, l1, h2, l2, h3, l3;
        split2(acc.x, h0, l0);
        split2(acc.y, h1, l1);
        split2(acc.z, h2, l2);
        split2(acc.w, h3, l3);
        ((ushort4*)(agg_hi + (size_t)node * F))[lane] = make_ushort4(h0, h1, h2, h3);
        ((ushort4*)(agg_lo + (size_t)node * F))[lane] = make_ushort4(l0, l1, l2, l3);
    }
}

// ---------------- W split + transpose: W[K][256] f32 -> Bt_hi/lo [256][K] bf16 ----------------

__global__ void split_w_kernel(const float* __restrict__ W, unsigned short* __restrict__ bhi,
                               unsigned short* __restrict__ blo, int K) {
    int i = blockIdx.x * 256 + threadIdx.x;
    if (i >= K * 256) return;
    int k = i >> 8;
    int n = i & 255;
    unsigned short h, l;
    split2(W[i], h, l);
    bhi[(size_t)n * K + k] = h;
    blo[(size_t)n * K + k] = l;
}

// ---------------- MFMA GEMM (split bf16, 3 products) + bias + ReLU ----------------
// out[M,256] = relu(A[M,K] @ W[K,256] + b). A given as hi/lo bf16 [M][K] (row-major),
// W as hi/lo bf16 [256][K] (transposed). 256 thr = 4 waves; wave w owns cols [64w,64w+64).
// All fragments loaded straight from global (L2-hot); no LDS, no barriers.
// mfma_f32_16x16x32_bf16: A-frag lane l: row=l&15, k=(l>>4)*8+j; B symmetric;
// C/D: col=lane&15, row=(lane>>4)*4+reg.

template<int K, bool RELU>
__global__ __launch_bounds__(256) void gemm_mfma_kernel(
    const unsigned short* __restrict__ Ahi, const unsigned short* __restrict__ Alo,
    const unsigned short* __restrict__ Bhi, const unsigned short* __restrict__ Blo,
    const float* __restrict__ bias, float* __restrict__ out, int M)
{
    int lane = threadIdx.x & 63;
    int wave = threadIdx.x >> 6;
    int row0 = blockIdx.x * 64;
    int col0 = wave * 64;
    int lr = lane & 15;
    int koff0 = (lane >> 4) * 8;

    f32x4 acc[4][4];
    #pragma unroll
    for (int i = 0; i < 4; ++i)
        #pragma unroll
        for (int j = 0; j < 4; ++j) acc[i][j] = (f32x4){0.f, 0.f, 0.f, 0.f};

    #pragma unroll 1
    for (int kk = 0; kk < K; kk += 32) {
        int ko = kk + koff0;
        short8 ah[4], al[4], bh[4], bl[4];
        #pragma unroll
        for (int t = 0; t < 4; ++t) {
            size_t aoff = (size_t)(row0 + t * 16 + lr) * K + ko;
            ah[t] = *(const short8*)(Ahi + aoff);
            al[t] = *(const short8*)(Alo + aoff);
            size_t boff = (size_t)(col0 + t * 16 + lr) * K + ko;
            bh[t] = *(const short8*)(Bhi + boff);
            bl[t] = *(const short8*)(Blo + boff);
        }
        #pragma unroll
        for (int mt = 0; mt < 4; ++mt)
            #pragma unroll
            for (int nt = 0; nt < 4; ++nt) {
                acc[mt][nt] = __builtin_amdgcn_mfma_f32_16x16x32_bf16(ah[mt], bh[nt], acc[mt][nt], 0, 0, 0);
                acc[mt][nt] = __builtin_amdgcn_mfma_f32_16x16x32_bf16(ah[mt], bl[nt], acc[mt][nt], 0, 0, 0);
                acc[mt][nt] = __builtin_amdgcn_mfma_f32_16x16x32_bf16(al[mt], bh[nt], acc[mt][nt], 0, 0, 0);
            }
    }

    int rgrp = (lane >> 4) * 4;
    #pragma unroll
    for (int mt = 0; mt < 4; ++mt) {
        #pragma unroll
        for (int nt = 0; nt < 4; ++nt) {
            int c = col0 + nt * 16 + lr;
            float bv = bias[c];
            #pragma unroll
            for (int reg = 0; reg < 4; ++reg) {
                int r = row0 + mt * 16 + rgrp + reg;
                if (r < M) {
                    float v = acc[mt][nt][reg] + bv;
                    if (RELU) v = fmaxf(v, 0.0f);
                    out[(size_t)r * 256 + c] = v;
                }
            }
        }
    }
}

// ---------------- dense head + softmax, LDS-staged ----------------

__global__ __launch_bounds__(256) void dense_softmax_kernel(const float* __restrict__ h,
                                                            const float* __restrict__ Wd,
                                                            const float* __restrict__ bd,
                                                            float* __restrict__ out, int M) {
    __shared__ float hs[32][260];
    __shared__ float wt[40][260];
    int tid = threadIdx.x;
    int row0 = blockIdx.x * 32;

    for (int i = tid; i < 40 * 256; i += 256) {
        int k = i / 40;
        int c = i - k * 40;
        wt[c][k] = Wd[i];
    }
    #pragma unroll
    for (int i = 0; i < 8; ++i) {
        int f = tid + i * 256;
        int r = f >> 6;
        int k4 = (f & 63) << 2;
        float4 v = make_float4(0.f, 0.f, 0.f, 0.f);
        if (row0 + r < M) v = *(const float4*)(h + (size_t)(row0 + r) * 256 + k4);
        *(float4*)&hs[r][k4] = v;
    }
    __syncthreads();

    int r  = tid >> 3;
    int cg = tid & 7;
    int c0 = cg * 5;

    float acc[5] = {0.f, 0.f, 0.f, 0.f, 0.f};
    #pragma unroll 4
    for (int k4 = 0; k4 < 64; ++k4) {
        float4 hv = *(float4*)&hs[r][k4 * 4];
        #pragma unroll
        for (int j = 0; j < 5; ++j) {
            float4 wv = *(float4*)&wt[c0 + j][k4 * 4];
            acc[j] = fmaf(hv.x, wv.x, acc[j]);
            acc[j] = fmaf(hv.y, wv.y, acc[j]);
            acc[j] = fmaf(hv.z, wv.z, acc[j]);
            acc[j] = fmaf(hv.w, wv.w, acc[j]);
        }
    }
    #pragma unroll
    for (int j = 0; j < 5; ++j) acc[j] += bd[c0 + j];

    float m = acc[0];
    #pragma unroll
    for (int j = 1; j < 5; ++j) m = fmaxf(m, acc[j]);
    #pragma unroll
    for (int off = 1; off < 8; off <<= 1) m = fmaxf(m, __shfl_xor(m, off));

    float e[5], s = 0.f;
    #pragma unroll
    for (int j = 0; j < 5; ++j) { e[j] = expf(acc[j] - m); s += e[j]; }
    #pragma unroll
    for (int off = 1; off < 8; off <<= 1) s += __shfl_xor(s, off);

    int row = row0 + r;
    if (row < M) {
        float inv_s = 1.0f / s;
        float* orow = out + (size_t)row * 40 + c0;
        #pragma unroll
        for (int j = 0; j < 5; ++j) orow[j] = e[j] * inv_s;
    }
}

// ---------------- launch ----------------

extern "C" void kernel_launch(void* const* d_in, const int* in_sizes, int n_in,
                              void* d_out, int out_size, void* d_ws, size_t ws_size,
                              hipStream_t stream) {
    const float* x  = (const float*)d_in[0];
    const int*   ei = (const int*)d_in[1];
    const float* W1 = (const float*)d_in[2];
    const float* b1 = (const float*)d_in[3];
    const float* W2 = (const float*)d_in[4];
    const float* b2 = (const float*)d_in[5];
    const float* Wd = (const float*)d_in[6];
    const float* bd = (const float*)d_in[7];
    float* out = (float*)d_out;

    const int N = N_NODES;
    const int E = in_sizes[1] / 2;
    const int* src = ei;
    const int* dst = ei + E;

    const int MP = 50048;   // M padded to multiple of 64 for MFMA tiles

    // workspace layout (bytes, 1KB-aligned). ~110 MB.
    char* ws = (char*)d_ws;
    size_t off = 0;
    auto alloc = [&](size_t bytes) { char* p = ws + off; off += (bytes + 1023) & ~(size_t)1023; return p; };
    int*   deg    = (int*)alloc((size_t)N * 4);
    float* inv    = (float*)alloc((size_t)N * 4);
    int*   rowptr = (int*)alloc((size_t)(N + 1) * 4);
    int*   cursor = (int*)alloc((size_t)N * 4);
    int*   bsum   = (int*)alloc((size_t)64 * 4);
    int*   src_s  = (int*)alloc((size_t)E * 4);
    float* norm_s = (float*)alloc((size_t)E * 4);
    float* h1     = (float*)alloc((size_t)N * 256 * 4);                    // h1 / h2 (f32)
    unsigned short* aggU = (unsigned short*)alloc((size_t)MP * 256 * 2 * 2); // union region
    unsigned short* w1hi = (unsigned short*)alloc((size_t)128 * 256 * 2);
    unsigned short* w1lo = (unsigned short*)alloc((size_t)128 * 256 * 2);
    unsigned short* w2hi = (unsigned short*)alloc((size_t)256 * 256 * 2);
    unsigned short* w2lo = (unsigned short*)alloc((size_t)256 * 256 * 2);

    // union aliases: agg1 (K=128) uses first half; agg2 (K=256) uses whole region
    unsigned short* agg1_hi = aggU;
    unsigned short* agg1_lo = aggU + (size_t)MP * 128;
    unsigned short* agg2_hi = aggU;
    unsigned short* agg2_lo = aggU + (size_t)MP * 256;
    float* h2 = h1;

    hipMemsetAsync(deg, 0, (size_t)N * 4, stream);

    const int nb = (N + 1023) / 1024;   // 49 scan blocks

    // degree -> inv_sqrt -> rowptr(+cursor) -> bucketed (src_s, norm_s)
    deg_kernel<<<(E + 255) / 256, 256, 0, stream>>>(dst, deg, E);
    inv_sqrt_kernel<<<(N + 255) / 256, 256, 0, stream>>>(deg, inv, N);
    scan_p1<<<nb, 256, 0, stream>>>(deg, bsum, N);
    scan_p2<<<1, 64, 0, stream>>>(bsum, nb, rowptr, N);
    scan_p3<<<nb, 256, 0, stream>>>(deg, bsum, rowptr, cursor, N);
    fill_kernel<<<(E + 255) / 256, 256, 0, stream>>>(src, dst, inv, cursor, src_s, norm_s, E);

    // pre-split weights (transposed)
    split_w_kernel<<<(128 * 256 + 255) / 256, 256, 0, stream>>>(W1, w1hi, w1lo, 128);
    split_w_kernel<<<(256 * 256 + 255) / 256, 256, 0, stream>>>(W2, w2hi, w2lo, 256);

    // conv1: gather into agg1 (split bf16), then h1 = relu(agg1 @ W1 + b1) via MFMA
    gather_agg_kernel<128><<<(N + 3) / 4, 256, 0, stream>>>(x, rowptr, src_s, norm_s, agg1_hi, agg1_lo);
    gemm_mfma_kernel<128, true><<<MP / 64, 256, 0, stream>>>(agg1_hi, agg1_lo, w1hi, w1lo, b1, h1, N);

    // conv2: gather h1 into agg2 (split bf16), then h2 = relu(agg2 @ W2 + b2) via MFMA
    gather_agg_kernel<256><<<(N + 3) / 4, 256, 0, stream>>>(h1, rowptr, src_s, norm_s, agg2_hi, agg2_lo);
    gemm_mfma_kernel<256, true><<<MP / 64, 256, 0, stream>>>(agg2_hi, agg2_lo, w2hi, w2lo, b2, h2, N);

    // dense + softmax (LDS-staged)
    dense_softmax_kernel<<<(N + 31) / 32, 256, 0, stream>>>(h2, Wd, bd, out, N);
}